// Round 22
// baseline (28.946 us; speedup 1.0000x reference)
//
#include <hip/hip_runtime.h>
#include <math.h>

#define HOP     128
#define SIGLEN  160000
#define NBLOCKS 16384
#define TWO_PI  6.2831853071795864f

// ---- packed fp32 (VOP3P) helpers (r14-verified encodings, verbatim) ----
__device__ __forceinline__ float2 pk_add(float2 a, float2 b) {        // (a.x+b.x, a.y+b.y)
    float2 d; asm("v_pk_add_f32 %0, %1, %2" : "=v"(d) : "v"(a), "v"(b)); return d;
}
__device__ __forceinline__ float2 pk_sub(float2 a, float2 b) {        // (a.x-b.x, a.y-b.y)
    float2 d; asm("v_pk_add_f32 %0, %1, %2 neg_lo:[0,1] neg_hi:[0,1]" : "=v"(d) : "v"(a), "v"(b)); return d;
}
__device__ __forceinline__ float2 pk_add_neghi(float2 a, float2 b) {  // (a.x+b.x, a.y-b.y)
    float2 d; asm("v_pk_add_f32 %0, %1, %2 neg_hi:[0,1]" : "=v"(d) : "v"(a), "v"(b)); return d;
}

// cmul(a,w) in 2 VOP3P ops (lane-verified, passed r14)
__device__ __forceinline__ float2 cmul(float2 a, float2 b) {
    float2 m, r;
    asm("v_pk_mul_f32 %0, %1, %2 op_sel:[1,1] op_sel_hi:[0,1] neg_lo:[1,0]"
        : "=v"(m) : "v"(a), "v"(b));
    asm("v_pk_fma_f32 %0, %1, %2, %3 op_sel:[0,0,0] op_sel_hi:[1,0,1]"
        : "=v"(r) : "v"(a), "v"(b), "v"(m));
    return r;
}
__device__ __forceinline__ float2 cmul_mi(float2 a) {   // a * (-i)
    return make_float2(a.y, -a.x);
}

// radix-4 DIF butterfly, swap-free via op_sel (lane-verified, passed r14)
__device__ __forceinline__ void r4c(float2 a, float2 b, float2 c, float2 d,
                                    float2& y0, float2& y1, float2& y2, float2& y3) {
    float2 t0 = pk_add(a, c), t1 = pk_sub(a, c);
    float2 t2 = pk_add(b, d), t3 = pk_sub(b, d);
    y0 = pk_add(t0, t2);
    y2 = pk_sub(t0, t2);
    asm("v_pk_add_f32 %0, %1, %2 op_sel:[0,1] op_sel_hi:[1,0] neg_hi:[0,1]"
        : "=v"(y1) : "v"(t1), "v"(t3));   // (t1.x + t3.y, t1.y - t3.x)
    asm("v_pk_add_f32 %0, %1, %2 op_sel:[0,1] op_sel_hi:[1,0] neg_lo:[0,1]"
        : "=v"(y3) : "v"(t1), "v"(t3));   // (t1.x - t3.y, t1.y + t3.x)
}

// 16-pt DFT fully in registers: j = 4a+b, k = c+4d
__device__ __forceinline__ void dft16(const float2* p, float2* q) {
    float2 u[4][4];  // u[c][b]
    #pragma unroll
    for (int b = 0; b < 4; ++b)
        r4c(p[b], p[4 + b], p[8 + b], p[12 + b], u[0][b], u[1][b], u[2][b], u[3][b]);
    const float C  = 0.70710678118654752f;
    const float c1 = 0.92387953251128676f, s1 = 0.38268343236508977f;
    u[1][1] = cmul(u[1][1], make_float2(c1, -s1));   // W16^1
    u[2][1] = cmul(u[2][1], make_float2(C, -C));     // W16^2
    u[3][1] = cmul(u[3][1], make_float2(s1, -c1));   // W16^3
    u[1][2] = cmul(u[1][2], make_float2(C, -C));     // W16^2
    u[2][2] = cmul_mi(u[2][2]);                      // W16^4 = -i
    u[3][2] = cmul(u[3][2], make_float2(-C, -C));    // W16^6
    u[1][3] = cmul(u[1][3], make_float2(s1, -c1));   // W16^3
    u[2][3] = cmul(u[2][3], make_float2(-C, -C));    // W16^6
    u[3][3] = cmul(u[3][3], make_float2(-c1, s1));   // W16^9
    #pragma unroll
    for (int c = 0; c < 4; ++c)
        r4c(u[c][0], u[c][1], u[c][2], u[c][3], q[c], q[c + 4], q[c + 8], q[c + 12]);
}

// unpack packed-rfft bin (r14-verified); fold 1/2 into log
__device__ __forceinline__ float2 unpack_log(float2 A, float2 B) {
    float2 f0 = pk_add_neghi(A, B);                   // (A.x+B.x, A.y-B.y)
    float2 f1;
    asm("v_pk_add_f32 %0, %1, %2 op_sel:[1,1] op_sel_hi:[0,0] neg_hi:[1,0]"
        : "=v"(f1) : "v"(A), "v"(B));                 // (A.y+B.y, -A.x+B.x)
    float p0 = f0.x * f0.x + f0.y * f0.y;
    float p1 = f1.x * f1.x + f1.y * f1.y;
    float l0 = 0.5f * __logf(p0) - 0.69314718f;
    float l1 = 0.5f * __logf(p1) - 0.69314718f;
    return make_float2(fminf(fmaxf(l0, -12.0f), 12.0f),
                       fminf(fmaxf(l1, -12.0f), 12.0f));
}

// Compiler-only fence (validated r10/r13/r14): single-wave WG, in-order DS pipe.
#define FENCE() asm volatile("" ::: "memory")

// 16384 one-wave one-shot blocks (GITER=1): block churn desynchronizes waves
// so fresh blocks' load phases overlap resident blocks' FFT phases — the
// cross-wave overlap that in-wave prefetch (r11/r17/r18/r20) couldn't afford.
// Body is r14 verbatim minus the group loop; tables cost ~120 cyc per row.
__global__ __launch_bounds__(64, 4) void spectro_kernel(const float* __restrict__ x,
                                                        float* __restrict__ out) {
    const int g    = blockIdx.x;          // group id: sig*32 + tq
    const int lane = threadIdx.x;
    const int row  = lane >> 4;           // 0..3
    const int n2   = lane & 15;

    __shared__ float2 lds[1092];          // 273 float2 per row (8.7 KB total)
    float2* Lrow = lds + 273 * row;

    const int t   = 4 * (g & 31) + row;
    const int sig = g >> 5;
    const float src_t = ((float)t + 0.5f) * (1250.0f / 128.0f) - 0.5f;
    const int   t0 = (int)src_t;          // src_t >= 4.38 -> trunc == floor
    const float ft = src_t - (float)t0;
    const float* xb = x + (long)sig * SIGLEN + (long)t0 * HOP + n2;

    // ---- issue the 24 stride-16 sample loads FIRST (overlap w/ table calc) ----
    float cur[24];
    #pragma unroll
    for (int k = 0; k < 24; ++k) cur[k] = xb[16 * k];

    // compact tables (computed while loads are in flight):
    //   wtab8[i] = hann(16*i + n2), i<8 ; hann(16*(i+8)+n2) = 1 - wtab8[i]
    //   tw[j]    = W256^{n2*(j+1)}, j<8 ; W256^{n2*k} (k>8) = tw[7]*tw[k-9]
    float  wtab8[8];
    float2 tw[8];
    #pragma unroll
    for (int i = 0; i < 8; ++i) {
        wtab8[i] = 0.5f - 0.5f * __cosf((float)(16 * i + n2) * (TWO_PI / 256.0f));
        float ang = (float)(n2 * (i + 1)) * (TWO_PI / 256.0f);
        tw[i] = make_float2(__cosf(ang), -__sinf(ang));
    }

    // ---- pack z[n1] = w*(frame0 + i*frame1), n = 16*n1 + n2 ----
    float2 z[16];
    #pragma unroll
    for (int n1 = 0; n1 < 16; ++n1) {
        float w = (n1 < 8) ? wtab8[n1] : 1.0f - wtab8[n1 - 8];
        z[n1] = make_float2(w * cur[n1], w * cur[n1 + 8]);
    }

    // ---- first 16-DFT (over n1) + cross twiddle W256^{n2*k1} ----
    float2 A[16];
    dft16(z, A);
    #pragma unroll
    for (int k1 = 1; k1 < 16; ++k1) {
        if (k1 <= 8) A[k1] = cmul(A[k1], tw[k1 - 1]);
        else         A[k1] = cmul(cmul(A[k1], tw[7]), tw[k1 - 9]);
    }

    // ---- the one transpose (intra-wave, in-order DS pipe) ----
    #pragma unroll
    for (int k1 = 0; k1 < 16; ++k1) Lrow[17 * k1 + n2] = A[k1];
    FENCE();
    float2 B[16];
    #pragma unroll
    for (int j = 0; j < 16; ++j) B[j] = Lrow[17 * n2 + j];
    FENCE();

    // ---- second 16-DFT (over n2) -> X[k1 + 16*k2], k1 = n2 ----
    float2 X16[16];
    dft16(B, X16);
    #pragma unroll
    for (int k2 = 0; k2 < 16; ++k2) Lrow[16 * k2 + n2] = X16[k2];
    FENCE();

    // ---- output: 4 mels per lane (m = 16j + n2) ----
    #pragma unroll
    for (int j = 0; j < 4; ++j) {
        const int m = 16 * j + n2;
        const float src_m = ((float)m + 0.5f) * (129.0f / 64.0f) - 0.5f;
        const int   m0 = (int)src_m;      // in [0,127]
        const float fm = src_m - (float)m0;
        float2 A0 = Lrow[m0];
        float2 A1 = Lrow[m0 + 1];
        float2 B0 = Lrow[(256 - m0) & 255];
        float2 B1 = Lrow[255 - m0];
        float2 L0 = unpack_log(A0, B0);
        float2 L1 = unpack_log(A1, B1);
        float va = L0.x + fm * (L1.x - L0.x);
        float vb = L0.y + fm * (L1.y - L0.y);
        float val = va + ft * (vb - va);
        val = fminf(fmaxf(val, -12.0f), 12.0f);
        out[(long)(4 * g + row) * 64 + m] = val;
    }
}

extern "C" void kernel_launch(void* const* d_in, const int* in_sizes, int n_in,
                              void* d_out, int out_size, void* d_ws, size_t ws_size,
                              hipStream_t stream) {
    const float* x = (const float*)d_in[0];
    float* out = (float*)d_out;
    spectro_kernel<<<dim3(NBLOCKS), dim3(64), 0, stream>>>(x, out);
}

// Round 23
// 27.993 us; speedup vs baseline: 1.0341x; 1.0341x over previous
//
#include <hip/hip_runtime.h>
#include <math.h>

#define HOP     128
#define SIGLEN  160000
#define NWAVES  4096
#define GITER   4
#define TWO_PI  6.2831853071795864f

// ---- packed fp32 (VOP3P) helpers ----
// op_sel:[..] picks which half of each src feeds the LO lane; op_sel_hi the HI
// lane. neg_lo/neg_hi negate that src's contribution to the lane. Defaults:
// op_sel all-0, op_sel_hi all-1 (lo<-lo, hi<-hi).
__device__ __forceinline__ float2 pk_add(float2 a, float2 b) {        // (a.x+b.x, a.y+b.y)
    float2 d; asm("v_pk_add_f32 %0, %1, %2" : "=v"(d) : "v"(a), "v"(b)); return d;
}
__device__ __forceinline__ float2 pk_sub(float2 a, float2 b) {        // (a.x-b.x, a.y-b.y)
    float2 d; asm("v_pk_add_f32 %0, %1, %2 neg_lo:[0,1] neg_hi:[0,1]" : "=v"(d) : "v"(a), "v"(b)); return d;
}
__device__ __forceinline__ float2 pk_add_neghi(float2 a, float2 b) {  // (a.x+b.x, a.y-b.y)
    float2 d; asm("v_pk_add_f32 %0, %1, %2 neg_hi:[0,1]" : "=v"(d) : "v"(a), "v"(b)); return d;
}

// cmul(a,w) in 2 VOP3P ops (lane-verified, passed r14/r21)
__device__ __forceinline__ float2 cmul(float2 a, float2 b) {
    float2 m, r;
    asm("v_pk_mul_f32 %0, %1, %2 op_sel:[1,1] op_sel_hi:[0,1] neg_lo:[1,0]"
        : "=v"(m) : "v"(a), "v"(b));
    asm("v_pk_fma_f32 %0, %1, %2, %3 op_sel:[0,0,0] op_sel_hi:[1,0,1]"
        : "=v"(r) : "v"(a), "v"(b), "v"(m));
    return r;
}
__device__ __forceinline__ float2 cmul_mi(float2 a) {   // a * (-i)
    return make_float2(a.y, -a.x);
}

// radix-4 DIF butterfly, swap-free via op_sel (lane-verified, passed r14/r21)
__device__ __forceinline__ void r4c(float2 a, float2 b, float2 c, float2 d,
                                    float2& y0, float2& y1, float2& y2, float2& y3) {
    float2 t0 = pk_add(a, c), t1 = pk_sub(a, c);
    float2 t2 = pk_add(b, d), t3 = pk_sub(b, d);
    y0 = pk_add(t0, t2);
    y2 = pk_sub(t0, t2);
    asm("v_pk_add_f32 %0, %1, %2 op_sel:[0,1] op_sel_hi:[1,0] neg_hi:[0,1]"
        : "=v"(y1) : "v"(t1), "v"(t3));   // (t1.x + t3.y, t1.y - t3.x)
    asm("v_pk_add_f32 %0, %1, %2 op_sel:[0,1] op_sel_hi:[1,0] neg_lo:[0,1]"
        : "=v"(y3) : "v"(t1), "v"(t3));   // (t1.x - t3.y, t1.y + t3.x)
}

// 16-pt DFT fully in registers: j = 4a+b, k = c+4d
__device__ __forceinline__ void dft16(const float2* p, float2* q) {
    float2 u[4][4];  // u[c][b]
    #pragma unroll
    for (int b = 0; b < 4; ++b)
        r4c(p[b], p[4 + b], p[8 + b], p[12 + b], u[0][b], u[1][b], u[2][b], u[3][b]);
    const float C  = 0.70710678118654752f;
    const float c1 = 0.92387953251128676f, s1 = 0.38268343236508977f;
    u[1][1] = cmul(u[1][1], make_float2(c1, -s1));   // W16^1
    u[2][1] = cmul(u[2][1], make_float2(C, -C));     // W16^2
    u[3][1] = cmul(u[3][1], make_float2(s1, -c1));   // W16^3
    u[1][2] = cmul(u[1][2], make_float2(C, -C));     // W16^2
    u[2][2] = cmul_mi(u[2][2]);                      // W16^4 = -i
    u[3][2] = cmul(u[3][2], make_float2(-C, -C));    // W16^6
    u[1][3] = cmul(u[1][3], make_float2(s1, -c1));   // W16^3
    u[2][3] = cmul(u[2][3], make_float2(-C, -C));    // W16^6
    u[3][3] = cmul(u[3][3], make_float2(-c1, s1));   // W16^9
    #pragma unroll
    for (int c = 0; c < 4; ++c)
        r4c(u[c][0], u[c][1], u[c][2], u[c][3], q[c], q[c + 4], q[c + 8], q[c + 12]);
}

// unpack packed-rfft bin: A=X[k], B=X[(256-k)&255].
//   2*f0 = (A.x+B.x, A.y-B.y)
//   2*f1 = (A.y+B.y, B.x-A.x)  via op_sel (lo<-A.y,B.y ; hi<-A.x,B.x, neg A)
// fold the 1/2 into the log: 0.5*log(|2f|^2) - ln2 = log|f|.
__device__ __forceinline__ float2 unpack_log(float2 A, float2 B) {
    float2 f0 = pk_add_neghi(A, B);                   // (A.x+B.x, A.y-B.y)
    float2 f1;
    asm("v_pk_add_f32 %0, %1, %2 op_sel:[1,1] op_sel_hi:[0,0] neg_hi:[1,0]"
        : "=v"(f1) : "v"(A), "v"(B));                 // (A.y+B.y, -A.x+B.x)
    float p0 = f0.x * f0.x + f0.y * f0.y;
    float p1 = f1.x * f1.x + f1.y * f1.y;
    float l0 = 0.5f * __logf(p0) - 0.69314718f;
    float l1 = 0.5f * __logf(p1) - 0.69314718f;
    return make_float2(fminf(fmaxf(l0, -12.0f), 12.0f),
                       fminf(fmaxf(l1, -12.0f), 12.0f));
}

// Compiler-only fence (validated r10/r13/r14/r21): single-wave WG, in-order DS pipe.
#define FENCE() asm volatile("" ::: "memory")

// 4096 one-wave blocks x 4 groups x 4 rows (16 lanes per row).
// Packed FFT-256 per row: dft16(regs) -> cross-twiddle -> LDS transpose ->
// dft16(regs) -> X in LDS -> logmag+bilinear outputs.  Packed-fp32 ALU.
// Best-measured configuration (28.1-28.6 us across runs). Nine structural
// variants (r16-r22) all regressed or were neutral; the per-iteration serial
// chain (~4.3k cyc x 16 lane-iters/SIMD) is the wall at 66% of HBM ceiling.
__global__ __launch_bounds__(64, 4) void spectro_kernel(const float* __restrict__ x,
                                                        float* __restrict__ out) {
    const int wv   = blockIdx.x;          // 0..4095
    const int lane = threadIdx.x;
    const int row  = lane >> 4;           // 0..3
    const int n2   = lane & 15;

    __shared__ float2 lds[1092];          // 273 float2 per row (8.7 KB total)
    float2* Lrow = lds + 273 * row;

    // compact tables:
    //   wtab8[i] = hann(16*i + n2), i<8 ; hann(16*(i+8)+n2) = 1 - wtab8[i]
    //   tw[j]    = W256^{n2*(j+1)}, j<8 ; W256^{n2*k} (k>8) = tw[7]*tw[k-9]
    float  wtab8[8];
    float2 tw[8];
    #pragma unroll
    for (int i = 0; i < 8; ++i) {
        wtab8[i] = 0.5f - 0.5f * __cosf((float)(16 * i + n2) * (TWO_PI / 256.0f));
        float ang = (float)(n2 * (i + 1)) * (TWO_PI / 256.0f);
        tw[i] = make_float2(__cosf(ang), -__sinf(ang));
    }

    #pragma unroll 1
    for (int it = 0; it < GITER; ++it) {
        const int g   = GITER * wv + it;  // group id: sig*32 + tq
        const int t   = 4 * (g & 31) + row;
        const int sig = g >> 5;
        const float src_t = ((float)t + 0.5f) * (1250.0f / 128.0f) - 0.5f;
        const int   t0 = (int)src_t;      // src_t >= 4.38 -> trunc == floor
        const float ft = src_t - (float)t0;
        const float* xb = x + (long)sig * SIGLEN + (long)t0 * HOP + n2;

        // ---- 24 stride-16 samples (covers frames t0 and t0+1) ----
        float cur[24];
        #pragma unroll
        for (int k = 0; k < 24; ++k) cur[k] = xb[16 * k];

        // ---- pack z[n1] = w*(frame0 + i*frame1), n = 16*n1 + n2 ----
        float2 z[16];
        #pragma unroll
        for (int n1 = 0; n1 < 16; ++n1) {
            float w = (n1 < 8) ? wtab8[n1] : 1.0f - wtab8[n1 - 8];
            z[n1] = make_float2(w * cur[n1], w * cur[n1 + 8]);
        }

        // ---- first 16-DFT (over n1) + cross twiddle W256^{n2*k1} ----
        float2 A[16];
        dft16(z, A);
        #pragma unroll
        for (int k1 = 1; k1 < 16; ++k1) {
            if (k1 <= 8) A[k1] = cmul(A[k1], tw[k1 - 1]);
            else         A[k1] = cmul(cmul(A[k1], tw[7]), tw[k1 - 9]);
        }

        // ---- the one transpose (intra-wave, in-order DS pipe) ----
        #pragma unroll
        for (int k1 = 0; k1 < 16; ++k1) Lrow[17 * k1 + n2] = A[k1];
        FENCE();
        float2 B[16];
        #pragma unroll
        for (int j = 0; j < 16; ++j) B[j] = Lrow[17 * n2 + j];
        FENCE();

        // ---- second 16-DFT (over n2) -> X[k1 + 16*k2], k1 = n2 ----
        float2 X16[16];
        dft16(B, X16);
        #pragma unroll
        for (int k2 = 0; k2 < 16; ++k2) Lrow[16 * k2 + n2] = X16[k2];
        FENCE();

        // ---- output: 4 mels per lane (m = 16j + n2) ----
        #pragma unroll
        for (int j = 0; j < 4; ++j) {
            const int m = 16 * j + n2;
            const float src_m = ((float)m + 0.5f) * (129.0f / 64.0f) - 0.5f;
            const int   m0 = (int)src_m;   // in [0,127]
            const float fm = src_m - (float)m0;
            float2 A0 = Lrow[m0];
            float2 A1 = Lrow[m0 + 1];
            float2 B0 = Lrow[(256 - m0) & 255];
            float2 B1 = Lrow[255 - m0];
            float2 L0 = unpack_log(A0, B0);
            float2 L1 = unpack_log(A1, B1);
            float va = L0.x + fm * (L1.x - L0.x);
            float vb = L0.y + fm * (L1.y - L0.y);
            float val = va + ft * (vb - va);
            val = fminf(fmaxf(val, -12.0f), 12.0f);
            out[(long)(4 * g + row) * 64 + m] = val;
        }
        FENCE();   // output reads ordered before next iteration's T writes
    }
}

extern "C" void kernel_launch(void* const* d_in, const int* in_sizes, int n_in,
                              void* d_out, int out_size, void* d_ws, size_t ws_size,
                              hipStream_t stream) {
    const float* x = (const float*)d_in[0];
    float* out = (float*)d_out;
    spectro_kernel<<<dim3(NWAVES), dim3(64), 0, stream>>>(x, out);
}